// Round 15
// baseline (482.078 us; speedup 1.0000x reference)
//
#include <hip/hip_runtime.h>

typedef unsigned int uint;
typedef unsigned short ushort;
typedef __attribute__((ext_vector_type(8))) short bhalf8;
typedef __attribute__((ext_vector_type(4))) float floatx4;

#define D_IN 256
#define NUNIT 256     // live hidden units (256:512 dead: h_new[:,256:] never read)
#define GN 1024       // gates N = 4 gates x 256 units
#define NSUP 512
#define BATCH_N 32768
#define LDA_A 768     // A_cat: [h_a(0:256) | r(256:512) | h_b(512:768)]

__device__ __forceinline__ ushort f2b(float f){
  union { float f; uint u; } x; x.f = f;
  uint r = (x.u + 0x7fffu + ((x.u >> 16) & 1u)) >> 16;
  return (ushort)r;
}
__device__ __forceinline__ float b2f(ushort u){
  union { uint u; float f; } x; x.u = ((uint)u) << 16;
  return x.f;
}
__device__ __forceinline__ float sigmf(float x){ return 1.0f / (1.0f + __expf(-x)); }
__device__ __forceinline__ float tanhfast(float x){ return 1.0f - 2.0f / (1.0f + __expf(2.0f * x)); }

// ---------------------------------------------------------------------------
// global->LDS staging with SOURCE PRE-SWIZZLE (m173).
// 64-wide rows: LDS[R][o] = G[R][o ^ (R&7)], o = 16B octet (verified r5).
// 32-wide rows: LDS[R][o] = G[R][o ^ ((R>>1)&3)] — 16 rows/call; read-side
// 2-way bank aliasing only (free, m136).
// ---------------------------------------------------------------------------
__device__ __forceinline__ void stage_rows8(
    ushort* lds_base, const ushort* __restrict__ g, int ld,
    long grow0, int lrow0, int k0, int lane)
{
  const int rsub = lane >> 3;
  const int oct  = (lane & 7) ^ rsub;
  const ushort* gp = g + (grow0 + lrow0 + rsub) * ld + k0 + (oct << 3);
  ushort* lp = lds_base + lrow0 * 64;
  __builtin_amdgcn_global_load_lds(
      (const __attribute__((address_space(1))) void*)gp,
      (__attribute__((address_space(3))) void*)lp, 16, 0, 0);
}

__device__ __forceinline__ void stage_rows16_32(
    ushort* lds_base, const ushort* __restrict__ g, int ld,
    long grow0, int lrow0, int k0, int lane)
{
  const int rsub = lane >> 2;                    // 0..15 rows
  const int oct  = (lane & 3) ^ ((rsub >> 1) & 3);
  const ushort* gp = g + (grow0 + lrow0 + rsub) * ld + k0 + (oct << 3);
  ushort* lp = lds_base + lrow0 * 32;
  __builtin_amdgcn_global_load_lds(
      (const __attribute__((address_space(1))) void*)gp,
      (__attribute__((address_space(3))) void*)lp, 16, 0, 0);
}

__device__ __forceinline__ void stage_swz4(
    ushort* lds, const ushort* __restrict__ g, int ld, int row0, int k0,
    int wave, int lane)
{
  #pragma unroll
  for (int q = 0; q < 4; q++)
    stage_rows8(lds, g, ld, row0, wave * 32 + q * 8, k0, lane);
}

__device__ __forceinline__ void stage_swz8(
    ushort* lds, const ushort* __restrict__ g, int ld, int row0, int k0,
    int wave, int lane)
{
  #pragma unroll
  for (int q = 0; q < 2; q++)
    stage_rows8(lds, g, ld, row0, wave * 16 + q * 8, k0, lane);
}

__device__ __forceinline__ bhalf8 frag_ld(const ushort* lds, int R, int O, int sx)
{
  return *reinterpret_cast<const bhalf8*>(&lds[R * 64 + (((O ^ sx) & 7) << 3)]);
}

__device__ __forceinline__ bhalf8 frag32_ld(const ushort* lds, int R, int O)
{
  return *reinterpret_cast<const bhalf8*>(&lds[R * 32 + (((O ^ (R >> 1)) & 3) << 3)]);
}

// 512-col-wide swizzled LDS tile read: col group g (64 cols), octet O in group.
__device__ __forceinline__ bhalf8 frag_ld512(const ushort* lds, int R, int g, int O, int sx)
{
  return *reinterpret_cast<const bhalf8*>(&lds[R * 512 + g * 64 + (((O ^ sx) & 7) << 3)]);
}

// ---------------------------------------------------------------------------
// Gq = q @ Wq^T + bias (K=256, N=1024 permuted) -> packed bf16 uint2 {i|f,g|o}.
// Epilogue also runs step-0 pointwise (fp32 query). (round-9 form, frozen)
// ---------------------------------------------------------------------------
__global__ __launch_bounds__(512) void gemm_gq_fused(
    const ushort* __restrict__ Qb,
    const ushort* __restrict__ Wq,
    const float4* __restrict__ biasp,
    uint2* __restrict__ Gq,
    float* __restrict__ cbuf,
    const float* __restrict__ query,
    ushort* __restrict__ Hhi,
    ushort* __restrict__ Hlo)
{
  __shared__ ushort SM[2][8192];

  const int tid  = threadIdx.x;
  const int lane = tid & 63;
  const int wave = tid >> 6;
  const int wrow = (wave >> 1) * 32;
  const int wcol = (wave & 1) * 64;
  const int wg = (blockIdx.x & 7) * (gridDim.x >> 3) + (blockIdx.x >> 3);
  const int bm = wg >> 3;
  const int bn = wg & 7;
  const int rowA0 = bm * 128;
  const int colB0 = bn * 128;

  floatx4 acc[2][4];
  #pragma unroll
  for (int m = 0; m < 2; m++)
    #pragma unroll
    for (int n = 0; n < 4; n++)
      acc[m][n] = (floatx4){0.f, 0.f, 0.f, 0.f};

  const int lr = lane & 15;
  const int lg = lane >> 4;
  const int sx = lane & 7;

  for (int k0 = 0; k0 < 256; k0 += 64) {
    stage_swz8(SM[0], Qb, 256, rowA0, k0, wave, lane);
    stage_swz8(SM[1], Wq, 256, colB0, k0, wave, lane);
    __syncthreads();
    #pragma unroll
    for (int ks = 0; ks < 2; ks++) {
      bhalf8 af[2], bfr[4];
      #pragma unroll
      for (int m = 0; m < 2; m++)
        af[m] = frag_ld(SM[0], wrow + m * 16 + lr, ks * 4 + lg, sx);
      #pragma unroll
      for (int n = 0; n < 4; n++)
        bfr[n] = frag_ld(SM[1], wcol + n * 16 + lr, ks * 4 + lg, sx);
      #pragma unroll
      for (int m = 0; m < 2; m++)
        #pragma unroll
        for (int n = 0; n < 4; n++)
          acc[m][n] = __builtin_amdgcn_mfma_f32_16x16x32_bf16(af[m], bfr[n], acc[m][n], 0, 0, 0);
    }
    __syncthreads();
  }

  ushort* ehi = (ushort*)SM[0];
  ushort* elo = ehi + 128 * 32;
  float*  ec  = (float*)SM[1];

  const int u_loc = (wave & 1) * 16 + lr;
  const int u     = bn * 32 + u_loc;
  const float4 b4 = biasp[u];
  #pragma unroll
  for (int m = 0; m < 2; m++) {
    #pragma unroll
    for (int rr = 0; rr < 4; rr++) {
      const int  rloc = wrow + m * 16 + lg * 4 + rr;
      const long row  = rowA0 + rloc;
      float pi = acc[m][0][rr] + b4.x;
      float pf = acc[m][1][rr] + b4.y;
      float pg = acc[m][2][rr] + b4.z;
      float po = acc[m][3][rr] + b4.w;
      uint2 pk;
      pk.x = (uint)f2b(pi) | ((uint)f2b(pf) << 16);
      pk.y = (uint)f2b(pg) | ((uint)f2b(po) << 16);
      Gq[row * NUNIT + u] = pk;
      float cn = sigmf(pi) * tanhfast(pg);
      ec[rloc * 32 + u_loc] = cn;
      float h = query[row * D_IN + u] + sigmf(po) * tanhfast(cn);
      ushort hh = f2b(h);
      ehi[rloc * 32 + u_loc] = hh;
      elo[rloc * 32 + u_loc] = f2b(h - b2f(hh));
    }
  }
  __syncthreads();
  const int u0 = bn * 32;
  {
    int row = tid >> 2, part = tid & 3;
    *(uint4*)(Hhi + (long)(rowA0 + row) * LDA_A + u0 + part * 8) = ((const uint4*)ehi)[tid];
    *(uint4*)(Hlo + (long)(rowA0 + row) * D_IN + u0 + part * 8) = ((const uint4*)elo)[tid];
  }
  #pragma unroll
  for (int i = tid; i < 1024; i += 512) {
    int row = i >> 3, part = i & 7;
    *(uint4*)(cbuf + (long)(rowA0 + row) * NUNIT + u0 + part * 4) = ((const uint4*)ec)[i];
  }
}

// ---------------------------------------------------------------------------
// Steps 1-3: gates = A @ Whh'^T + Gq; fused LSTM pointwise.
// Single-barrier double-buffered K-loop (round-13 form, verified; frozen).
// ---------------------------------------------------------------------------
__global__ __launch_bounds__(512) void gemm_gates_fused(
    const ushort* __restrict__ A,
    const ushort* __restrict__ W,
    const uint2* __restrict__ Gq,
    float* __restrict__ cbuf,
    const float* __restrict__ query,
    ushort* __restrict__ Hhi,
    ushort* __restrict__ Hlo)
{
  __shared__ ushort SM[2][2][8192];

  const int tid  = threadIdx.x;
  const int lane = tid & 63;
  const int wave = tid >> 6;
  const int wrow = (wave >> 1) * 32;
  const int wcol = (wave & 1) * 64;
  const int wg = (blockIdx.x & 7) * (gridDim.x >> 3) + (blockIdx.x >> 3);
  const int bm = wg >> 3;
  const int bn = wg & 7;
  const int rowA0 = bm * 128;
  const int colB0 = bn * 128;

  floatx4 acc[2][4];
  #pragma unroll
  for (int m = 0; m < 2; m++)
    #pragma unroll
    for (int n = 0; n < 4; n++)
      acc[m][n] = (floatx4){0.f, 0.f, 0.f, 0.f};

  const int lr = lane & 15;
  const int lg = lane >> 4;
  const int sx = lane & 7;

  stage_swz8(SM[0][0], A, LDA_A, rowA0, 0, wave, lane);
  stage_swz8(SM[0][1], W, 512,   colB0, 0, wave, lane);
  __syncthreads();

  for (int t = 0; t < 8; t++) {
    const int cur = t & 1;
    if (t + 1 < 8) {
      stage_swz8(SM[cur ^ 1][0], A, LDA_A, rowA0, (t + 1) * 64, wave, lane);
      stage_swz8(SM[cur ^ 1][1], W, 512,   colB0, (t + 1) * 64, wave, lane);
    }
    const ushort* As = SM[cur][0];
    const ushort* Bs = SM[cur][1];
    #pragma unroll
    for (int ks = 0; ks < 2; ks++) {
      bhalf8 af[2], bfr[4];
      #pragma unroll
      for (int m = 0; m < 2; m++)
        af[m] = frag_ld(As, wrow + m * 16 + lr, ks * 4 + lg, sx);
      #pragma unroll
      for (int n = 0; n < 4; n++)
        bfr[n] = frag_ld(Bs, wcol + n * 16 + lr, ks * 4 + lg, sx);
      #pragma unroll
      for (int m = 0; m < 2; m++)
        #pragma unroll
        for (int n = 0; n < 4; n++)
          acc[m][n] = __builtin_amdgcn_mfma_f32_16x16x32_bf16(af[m], bfr[n], acc[m][n], 0, 0, 0);
    }
    __syncthreads();
  }

  ushort* ehi = (ushort*)SM[0][0];
  ushort* elo = ehi + 128 * 32;
  float*  ec  = (float*)SM[0][1];

  const int u_loc = (wave & 1) * 16 + lr;
  const int u     = bn * 32 + u_loc;
  #pragma unroll
  for (int m = 0; m < 2; m++) {
    #pragma unroll
    for (int rr = 0; rr < 4; rr++) {
      const int  rloc = wrow + m * 16 + lg * 4 + rr;
      const long row  = rowA0 + rloc;
      uint2 pk = Gq[row * NUNIT + u];
      float pi = acc[m][0][rr] + b2f((ushort)(pk.x & 0xffff));
      float pf = acc[m][1][rr] + b2f((ushort)(pk.x >> 16));
      float pg = acc[m][2][rr] + b2f((ushort)(pk.y & 0xffff));
      float po = acc[m][3][rr] + b2f((ushort)(pk.y >> 16));
      float cn = sigmf(pf) * cbuf[row * NUNIT + u] + sigmf(pi) * tanhfast(pg);
      ec[rloc * 32 + u_loc] = cn;
      float h = query[row * D_IN + u] + sigmf(po) * tanhfast(cn);
      ushort hh = f2b(h);
      ehi[rloc * 32 + u_loc] = hh;
      elo[rloc * 32 + u_loc] = f2b(h - b2f(hh));
    }
  }
  __syncthreads();
  const int u0 = bn * 32;
  {
    int row = tid >> 2, part = tid & 3;
    *(uint4*)(Hhi + (long)(rowA0 + row) * LDA_A + u0 + part * 8) = ((const uint4*)ehi)[tid];
    *(uint4*)(Hlo + (long)(rowA0 + row) * D_IN + u0 + part * 8) = ((const uint4*)elo)[tid];
  }
  #pragma unroll
  for (int i = tid; i < 1024; i += 512) {
    int row = i >> 3, part = i & 7;
    *(uint4*)(cbuf + (long)(rowA0 + row) * NUNIT + u0 + part * 4) = ((const uint4*)ec)[i];
  }
}

// ---------------------------------------------------------------------------
// Split-precision scores GEMM -> d_out fp32 (FINAL step only; round-9 form).
// ---------------------------------------------------------------------------
__global__ __launch_bounds__(256) void gemm_scores(
    const ushort* __restrict__ Ahi,
    const ushort* __restrict__ Alo,
    const ushort* __restrict__ Bhi, const ushort* __restrict__ Blo,
    float* __restrict__ C)
{
  __shared__ ushort AsH[128 * 64];
  __shared__ ushort AsL[128 * 64];
  __shared__ ushort BsH[128 * 64];
  __shared__ ushort BsL[128 * 64];

  const int tid  = threadIdx.x;
  const int lane = tid & 63;
  const int wave = tid >> 6;
  const int wr = (wave >> 1) * 64;
  const int wc = (wave & 1) * 64;
  const int wg = (blockIdx.x & 7) * (gridDim.x >> 3) + (blockIdx.x >> 3);
  const int bm = wg >> 2;
  const int bn = wg & 3;
  const int rowA0 = bm * 128;
  const int rowB0 = bn * 128;

  floatx4 acc[4][4];
  #pragma unroll
  for (int m = 0; m < 4; m++)
    #pragma unroll
    for (int n = 0; n < 4; n++)
      acc[m][n] = (floatx4){0.f, 0.f, 0.f, 0.f};

  const int lr = lane & 15;
  const int lg = lane >> 4;
  const int sx = lane & 7;

  for (int k0 = 0; k0 < D_IN; k0 += 64) {
    stage_swz4(AsH, Ahi, LDA_A, rowA0, k0, wave, lane);
    stage_swz4(AsL, Alo, D_IN,  rowA0, k0, wave, lane);
    stage_swz4(BsH, Bhi, D_IN,  rowB0, k0, wave, lane);
    stage_swz4(BsL, Blo, D_IN,  rowB0, k0, wave, lane);
    __syncthreads();
    #pragma unroll
    for (int ks = 0; ks < 2; ks++) {
      bhalf8 afh[4], afl[4], bfh[4], bfl[4];
      #pragma unroll
      for (int m = 0; m < 4; m++) {
        afh[m] = frag_ld(AsH, wr + m * 16 + lr, ks * 4 + lg, sx);
        afl[m] = frag_ld(AsL, wr + m * 16 + lr, ks * 4 + lg, sx);
      }
      #pragma unroll
      for (int n = 0; n < 4; n++) {
        bfh[n] = frag_ld(BsH, wc + n * 16 + lr, ks * 4 + lg, sx);
        bfl[n] = frag_ld(BsL, wc + n * 16 + lr, ks * 4 + lg, sx);
      }
      #pragma unroll
      for (int m = 0; m < 4; m++)
        #pragma unroll
        for (int n = 0; n < 4; n++) {
          acc[m][n] = __builtin_amdgcn_mfma_f32_16x16x32_bf16(afl[m], bfh[n], acc[m][n], 0, 0, 0);
          acc[m][n] = __builtin_amdgcn_mfma_f32_16x16x32_bf16(afh[m], bfl[n], acc[m][n], 0, 0, 0);
          acc[m][n] = __builtin_amdgcn_mfma_f32_16x16x32_bf16(afh[m], bfh[n], acc[m][n], 0, 0, 0);
        }
    }
    __syncthreads();
  }

  #pragma unroll
  for (int m = 0; m < 4; m++)
    #pragma unroll
    for (int n = 0; n < 4; n++)
      #pragma unroll
      for (int r = 0; r < 4; r++) {
        int row = rowA0 + wr + m * 16 + lg * 4 + r;
        int col = rowB0 + wc + n * 16 + lr;
        C[(long)row * NSUP + col] = acc[m][n][r];
      }
}

// ---------------------------------------------------------------------------
// Fused scores + softmax + PV for steps 0-2. M=32 rows/block, 64 KB LDS
// (2 blocks/CU), grid 1024. Phase 1: split scores GEMM, A hi/lo resident
// (32 KB), S staged in K=32 chunks [512][32] (32 KB, frag32 swizzle).
// Phase 2: softmax in two 16-row halves (scf fp32 in S region), P -> A region
// swizzled. Phase 3: PV (k_spv loop, verbatim operand mapping).
// Region map: A[0..16383]=A tiles -> P ; S[16384..32767]=S chunk -> scf ->
// STb chunk -> elr. All transitions barrier-protected.
// ---------------------------------------------------------------------------
__global__ __launch_bounds__(512) void k_sspv(
    const ushort* __restrict__ Ahi,   // Abuf + hoff (ld 768)
    const ushort* __restrict__ Alo,   // Hlo (ld 256)
    const ushort* __restrict__ Shi,   // [512][256]
    const ushort* __restrict__ Slo,   // [512][256]
    const ushort* __restrict__ STb,   // [256][512]
    ushort* __restrict__ Cv)          // Abuf + 256 (ldc LDA_A)
{
  __shared__ ushort SMEM[32768];      // 64 KB
  ushort* Sbuf = SMEM + 16384;        // [512][32] S chunk (32 KB)

  const int tid  = threadIdx.x;
  const int lane = tid & 63;
  const int wave = tid >> 6;
  const int wg = (blockIdx.x & 7) * (gridDim.x >> 3) + (blockIdx.x >> 3);
  const long rowA0 = (long)wg * 32;

  const int lr = lane & 15;
  const int lg = lane >> 4;
  const int sx = lane & 7;

  // ---- stage A: hi tiles (waves 0-3) / lo tiles (waves 4-7), [32][64] each ----
  {
    const ushort* asrc = (wave < 4) ? Ahi : Alo;
    const int ald = (wave < 4) ? LDA_A : D_IN;
    ushort* adst = SMEM + (wave >> 2) * 8192 + (wave & 3) * 2048;
    const int ak0 = (wave & 3) * 64;
    #pragma unroll
    for (int q = 0; q < 4; q++)
      stage_rows8(adst, asrc, ald, rowA0, q * 8, ak0, lane);
  }
  // first Shi chunk (kc=0): 512 rows x 32 K-cols
  #pragma unroll
  for (int q = 0; q < 4; q++)
    stage_rows16_32(Sbuf, Shi, D_IN, 0, wave * 64 + q * 16, 0, lane);
  __syncthreads();

  floatx4 acc[2][4];
  #pragma unroll
  for (int m = 0; m < 2; m++)
    #pragma unroll
    for (int n = 0; n < 4; n++)
      acc[m][n] = (floatx4){0.f, 0.f, 0.f, 0.f};

  for (int kc = 0; kc < 8; kc++) {
    const ushort* Ah = SMEM + (kc >> 1) * 2048;
    const ushort* Al = SMEM + 8192 + (kc >> 1) * 2048;
    const int O = (kc & 1) * 4 + lg;
    bhalf8 afh[2], afl[2], bf[4];
    #pragma unroll
    for (int m = 0; m < 2; m++) {
      afh[m] = frag_ld(Ah, m * 16 + lr, O, sx);
      afl[m] = frag_ld(Al, m * 16 + lr, O, sx);
    }
    // hi pass: afl*Shi + afh*Shi
    #pragma unroll
    for (int n = 0; n < 4; n++)
      bf[n] = frag32_ld(Sbuf, wave * 64 + n * 16 + lr, lg);
    #pragma unroll
    for (int m = 0; m < 2; m++)
      #pragma unroll
      for (int n = 0; n < 4; n++) {
        acc[m][n] = __builtin_amdgcn_mfma_f32_16x16x32_bf16(afl[m], bf[n], acc[m][n], 0, 0, 0);
        acc[m][n] = __builtin_amdgcn_mfma_f32_16x16x32_bf16(afh[m], bf[n], acc[m][n], 0, 0, 0);
      }
    __syncthreads();
    #pragma unroll
    for (int q = 0; q < 4; q++)
      stage_rows16_32(Sbuf, Slo, D_IN, 0, wave * 64 + q * 16, kc * 32, lane);
    __syncthreads();
    // lo pass: afh*Slo
    #pragma unroll
    for (int n = 0; n < 4; n++)
      bf[n] = frag32_ld(Sbuf, wave * 64 + n * 16 + lr, lg);
    #pragma unroll
    for (int m = 0; m < 2; m++)
      #pragma unroll
      for (int n = 0; n < 4; n++)
        acc[m][n] = __builtin_amdgcn_mfma_f32_16x16x32_bf16(afh[m], bf[n], acc[m][n], 0, 0, 0);
    __syncthreads();
    if (kc < 7) {
      #pragma unroll
      for (int q = 0; q < 4; q++)
        stage_rows16_32(Sbuf, Shi, D_IN, 0, wave * 64 + q * 16, (kc + 1) * 32, lane);
      __syncthreads();
    }
  }

  // ---- phase 2: softmax in two 16-row halves; P -> A region (swizzled) ----
  float*  scf = (float*)Sbuf;          // [16][512] fp32 = 32 KB
  ushort* Ps  = SMEM;                  // [32][512] bf16 = 32 KB
  const int po  = (lane >> 1) & 7;
  const int ph4 = (lane & 1) * 4;
  const int pg0 = lane >> 4;

  #pragma unroll
  for (int half = 0; half < 2; half++) {
    #pragma unroll
    for (int n = 0; n < 4; n++)
      #pragma unroll
      for (int r = 0; r < 4; r++)
        scf[(lg * 4 + r) * 512 + wave * 64 + n * 16 + lr] = acc[half][n][r];
    __syncthreads();
    #pragma unroll
    for (int j = 0; j < 2; j++) {
      const int rl = wave * 2 + j;          // 0..15 within half
      const int r  = half * 16 + rl;        // local row 0..31
      const float4* sp = reinterpret_cast<const float4*>(scf + rl * 512);
      float4 v0 = sp[lane];
      float4 v1 = sp[64 + lane];
      float m = fmaxf(fmaxf(fmaxf(v0.x, v0.y), fmaxf(v0.z, v0.w)),
                      fmaxf(fmaxf(v1.x, v1.y), fmaxf(v1.z, v1.w)));
      #pragma unroll
      for (int off = 32; off >= 1; off >>= 1) m = fmaxf(m, __shfl_xor(m, off));
      float e0 = __expf(v0.x - m), e1 = __expf(v0.y - m), e2 = __expf(v0.z - m), e3 = __expf(v0.w - m);
      float e4 = __expf(v1.x - m), e5 = __expf(v1.y - m), e6 = __expf(v1.z - m), e7 = __expf(v1.w - m);
      float s = e0 + e1 + e2 + e3 + e4 + e5 + e6 + e7;
      #pragma unroll
      for (int off = 32; off >= 1; off >>= 1) s += __shfl_xor(s, off);
      float inv = 1.0f / s;
      uint2 p0, p1;
      p0.x = (uint)f2b(e0 * inv) | ((uint)f2b(e1 * inv) << 16);
      p0.y = (uint)f2b(e2 * inv) | ((uint)f2b(e3 * inv) << 16);
      p1.x = (uint)f2b(e4 * inv) | ((uint)f2b(e5 * inv) << 16);
      p1.y = (uint)f2b(e6 * inv) | ((uint)f2b(e7 * inv) << 16);
      const int os = ((po ^ (r & 7)) << 3) + ph4;
      *(uint2*)&Ps[r * 512 + (pg0    ) * 64 + os] = p0;
      *(uint2*)&Ps[r * 512 + (pg0 + 4) * 64 + os] = p1;
    }
    __syncthreads();
  }

  // ---- phase 3: r = P @ STb^T (k_spv loop) ----
  floatx4 pacc[2][2];
  #pragma unroll
  for (int m = 0; m < 2; m++)
    #pragma unroll
    for (int n = 0; n < 2; n++)
      pacc[m][n] = (floatx4){0.f, 0.f, 0.f, 0.f};

  ushort* Bpv = SMEM + 16384;          // [256][64] chunk (32 KB)
  for (int kc = 0; kc < 8; kc++) {
    #pragma unroll
    for (int q = 0; q < 4; q++)
      stage_rows8(Bpv, STb, NSUP, 0, wave * 32 + q * 8, kc * 64, lane);
    __syncthreads();
    #pragma unroll
    for (int ks = 0; ks < 2; ks++) {
      bhalf8 af[2], bfr[2];
      #pragma unroll
      for (int m = 0; m < 2; m++)
        af[m] = frag_ld512(Ps, m * 16 + lr, kc, ks * 4 + lg, sx);
      #pragma unroll
      for (int n = 0; n < 2; n++)
        bfr[n] = frag_ld(Bpv, wave * 32 + n * 16 + lr, ks * 4 + lg, sx);
      #pragma unroll
      for (int m = 0; m < 2; m++)
        #pragma unroll
        for (int n = 0; n < 2; n++)
          pacc[m][n] = __builtin_amdgcn_mfma_f32_16x16x32_bf16(af[m], bfr[n], pacc[m][n], 0, 0, 0);
    }
    __syncthreads();
  }

  // ---- epilogue: r [32][256] bf16 via LDS (S region), coalesced writeout ----
  ushort* elr = SMEM + 16384;
  #pragma unroll
  for (int m = 0; m < 2; m++)
    #pragma unroll
    for (int n = 0; n < 2; n++)
      #pragma unroll
      for (int r = 0; r < 4; r++)
        elr[(m * 16 + lg * 4 + r) * 256 + wave * 32 + n * 16 + lr] = f2b(pacc[m][n][r]);
  __syncthreads();
  #pragma unroll
  for (int i = tid; i < 1024; i += 512) {
    int row = i >> 5, part = i & 31;
    *(uint4*)(Cv + (rowA0 + row) * LDA_A + part * 8) = ((const uint4*)elr)[i];
  }
}

// ---------------------------------------------------------------------------
// Build permuted live-unit weights + bias + S hi/lo + S^T. (unchanged)
// ---------------------------------------------------------------------------
__global__ __launch_bounds__(256) void k_build(
    const float* __restrict__ Wih, const float* __restrict__ Whh,
    const float* __restrict__ bih, const float* __restrict__ bhh,
    const float* __restrict__ S,
    ushort* __restrict__ We, ushort* __restrict__ Wo, ushort* __restrict__ Wq,
    float4* __restrict__ biasp,
    ushort* __restrict__ Shi, ushort* __restrict__ Slo,
    ushort* __restrict__ STb)
{
  int t = blockIdx.x * 256 + threadIdx.x;
  if (t < GN * 512) {
    int c = t >> 9, k = t & 511;
    int unit = (c >> 6) * 16 + (c & 15);
    int gate = (c >> 4) & 3;
    long srow = (long)(gate * 512 + unit);
    We[(long)c * 512 + k] = f2b(Whh[srow * 512 + k]);
    int ko = (k < 256) ? (256 + k) : (k - 256);
    Wo[(long)c * 512 + k] = f2b(Whh[srow * 512 + ko]);
    if (k < 256) Wq[(long)c * 256 + k] = f2b(Wih[srow * 256 + k]);
  }
  if (t < NUNIT) {
    biasp[t] = make_float4(bih[t] + bhh[t],
                           bih[512 + t] + bhh[512 + t],
                           bih[1024 + t] + bhh[1024 + t],
                           bih[1536 + t] + bhh[1536 + t]);
  }
  if (t < NSUP * D_IN) {
    float v = S[t];
    ushort hv = f2b(v);
    Shi[t] = hv;
    Slo[t] = f2b(v - b2f(hv));
    int s = t >> 8, d = t & 255;
    STb[(long)d * NSUP + s] = hv;
  }
}

// bf16 copy of query (GEMM operand only; epilogues use fp32 query).
__global__ __launch_bounds__(256) void k_initq(
    const float* __restrict__ query, ushort* __restrict__ Qb)
{
  long t = (long)blockIdx.x * 256 + threadIdx.x;
  Qb[t] = f2b(query[t]);
}

// ---------------------------------------------------------------------------
extern "C" void kernel_launch(void* const* d_in, const int* in_sizes, int n_in,
                              void* d_out, int out_size, void* d_ws, size_t ws_size,
                              hipStream_t stream)
{
  const float* support_mean = (const float*)d_in[0];
  const float* query_mean   = (const float*)d_in[2];
  const float* W_ih = (const float*)d_in[4];
  const float* W_hh = (const float*)d_in[5];
  const float* b_ih = (const float*)d_in[6];
  const float* b_hh = (const float*)d_in[7];
  float* out = (float*)d_out;

  char* ws = (char*)d_ws;
  size_t off = 0;
  auto alloc = [&](size_t bytes) {
    void* p = ws + off;
    off += (bytes + 255) & ~(size_t)255;
    return p;
  };
  ushort* Abuf  = (ushort*)alloc((size_t)BATCH_N * LDA_A * 2);  // 50.3 MB
  ushort* Qb    = (ushort*)alloc((size_t)BATCH_N * D_IN * 2);   // 16.8 MB
  ushort* We    = (ushort*)alloc((size_t)GN * 512 * 2);         // 1.05 MB
  ushort* Wo    = (ushort*)alloc((size_t)GN * 512 * 2);         // 1.05 MB
  ushort* Wq    = (ushort*)alloc((size_t)GN * 256 * 2);         // 0.52 MB
  float4* biasp = (float4*)alloc((size_t)NUNIT * 16);
  ushort* Shi   = (ushort*)alloc((size_t)NSUP * D_IN * 2);
  ushort* Slo   = (ushort*)alloc((size_t)NSUP * D_IN * 2);
  ushort* STb   = (ushort*)alloc((size_t)D_IN * NSUP * 2);
  float*  cbuf  = (float*) alloc((size_t)BATCH_N * NUNIT * 4);  // 33.6 MB
  ushort* Hlo   = (ushort*)alloc((size_t)BATCH_N * D_IN * 2);   // 16.8 MB
  uint2*  Gq    = (uint2*) alloc((size_t)BATCH_N * NUNIT * 8);  // 67.1 MB
  if (off > ws_size) return;  // total ~189 MB; >=255 MB proven available

  hipLaunchKernelGGL(k_build, dim3((GN * 512) / 256), dim3(256), 0, stream,
                     W_ih, W_hh, b_ih, b_hh, support_mean,
                     We, Wo, Wq, biasp, Shi, Slo, STb);
  hipLaunchKernelGGL(k_initq, dim3((BATCH_N * D_IN) / 256), dim3(256), 0, stream,
                     query_mean, Qb);

  // Gq = q@Wq^T + b (shared by all steps) + step-0 pointwise -> h_a, c.
  hipLaunchKernelGGL(gemm_gq_fused,
                     dim3((BATCH_N / 128) * (GN / 128)), dim3(512), 0, stream,
                     Qb, Wq, biasp, Gq, cbuf, query_mean, Abuf + 0, Hlo);

  // steps 0-2: fused scores+softmax+PV (no d_out traffic), then next gates.
  for (int s = 0; s < 3; s++) {
    const int hoff = (s & 1) * 512;   // h slot of step s
    hipLaunchKernelGGL(k_sspv, dim3(BATCH_N / 32), dim3(512), 0, stream,
                       Abuf + hoff, Hlo, Shi, Slo, STb, Abuf + 256);
    const int aoff = ((s + 1) == 2) ? 256 : 0;
    const ushort* Wnext = ((s + 1) == 2) ? Wo : We;
    hipLaunchKernelGGL(gemm_gates_fused,
                       dim3((BATCH_N / 128) * (GN / 128)), dim3(512), 0, stream,
                       Abuf + aoff, Wnext, Gq, cbuf, query_mean,
                       Abuf + ((s + 1) & 1) * 512, Hlo);
  }
  // step 3: final scores -> d_out (h in h_b slot, hoff 512)
  hipLaunchKernelGGL(gemm_scores,
                     dim3((BATCH_N / 128) * (NSUP / 128)), dim3(256), 0, stream,
                     Abuf + 512, Hlo, Shi, Slo, out);
}

// Round 17
// 456.097 us; speedup vs baseline: 1.0570x; 1.0570x over previous
//
#include <hip/hip_runtime.h>

typedef unsigned int uint;
typedef unsigned short ushort;
typedef __attribute__((ext_vector_type(8))) short bhalf8;
typedef __attribute__((ext_vector_type(4))) float floatx4;

#define D_IN 256
#define NUNIT 256     // live hidden units (256:512 dead: h_new[:,256:] never read)
#define GN 1024       // gates N = 4 gates x 256 units
#define NSUP 512
#define BATCH_N 32768
#define LDA_A 768     // A_cat: [h_a(0:256) | r(256:512) | h_b(512:768)]

__device__ __forceinline__ ushort f2b(float f){
  union { float f; uint u; } x; x.f = f;
  uint r = (x.u + 0x7fffu + ((x.u >> 16) & 1u)) >> 16;
  return (ushort)r;
}
__device__ __forceinline__ float b2f(ushort u){
  union { uint u; float f; } x; x.u = ((uint)u) << 16;
  return x.f;
}
__device__ __forceinline__ float sigmf(float x){ return 1.0f / (1.0f + __expf(-x)); }
__device__ __forceinline__ float tanhfast(float x){ return 1.0f - 2.0f / (1.0f + __expf(2.0f * x)); }

// ---------------------------------------------------------------------------
// global->LDS staging with SOURCE PRE-SWIZZLE (m173): LDS linear; lane fetches
// global octet (lane&7)^(lane>>3) so LDS[R][o] = G[R][o ^ (R&7)]; reads apply
// the same XOR (frag_ld). Verified round 5: bank conflicts 3.8e7 -> 0.
// ---------------------------------------------------------------------------
__device__ __forceinline__ void stage_rows8(
    ushort* lds_base, const ushort* __restrict__ g, int ld,
    long grow0, int lrow0, int k0, int lane)
{
  const int rsub = lane >> 3;
  const int oct  = (lane & 7) ^ rsub;
  const ushort* gp = g + (grow0 + lrow0 + rsub) * ld + k0 + (oct << 3);
  ushort* lp = lds_base + lrow0 * 64;
  __builtin_amdgcn_global_load_lds(
      (const __attribute__((address_space(1))) void*)gp,
      (__attribute__((address_space(3))) void*)lp, 16, 0, 0);
}

__device__ __forceinline__ void stage_swz4(
    ushort* lds, const ushort* __restrict__ g, int ld, int row0, int k0,
    int wave, int lane)
{
  #pragma unroll
  for (int q = 0; q < 4; q++)
    stage_rows8(lds, g, ld, row0, wave * 32 + q * 8, k0, lane);
}

__device__ __forceinline__ void stage_swz8(
    ushort* lds, const ushort* __restrict__ g, int ld, int row0, int k0,
    int wave, int lane)
{
  #pragma unroll
  for (int q = 0; q < 2; q++)
    stage_rows8(lds, g, ld, row0, wave * 16 + q * 8, k0, lane);
}

__device__ __forceinline__ bhalf8 frag_ld(const ushort* lds, int R, int O, int sx)
{
  return *reinterpret_cast<const bhalf8*>(&lds[R * 64 + (((O ^ sx) & 7) << 3)]);
}

// 512-col-wide swizzled LDS tile read: col group g (64 cols), octet O in group.
__device__ __forceinline__ bhalf8 frag_ld512(const ushort* lds, int R, int g, int O, int sx)
{
  return *reinterpret_cast<const bhalf8*>(&lds[R * 512 + g * 64 + (((O ^ sx) & 7) << 3)]);
}

// ---------------------------------------------------------------------------
// Gq = q @ Wq^T + bias (K=256, N=1024 permuted) -> packed bf16 uint2 {i|f,g|o}.
// Epilogue also runs step-0 pointwise (fp32 query). (round-9 form, frozen)
// ---------------------------------------------------------------------------
__global__ __launch_bounds__(512) void gemm_gq_fused(
    const ushort* __restrict__ Qb,
    const ushort* __restrict__ Wq,
    const float4* __restrict__ biasp,
    uint2* __restrict__ Gq,
    float* __restrict__ cbuf,
    const float* __restrict__ query,
    ushort* __restrict__ Hhi,
    ushort* __restrict__ Hlo)
{
  __shared__ ushort SM[2][8192];

  const int tid  = threadIdx.x;
  const int lane = tid & 63;
  const int wave = tid >> 6;
  const int wrow = (wave >> 1) * 32;
  const int wcol = (wave & 1) * 64;
  const int wg = (blockIdx.x & 7) * (gridDim.x >> 3) + (blockIdx.x >> 3);
  const int bm = wg >> 3;
  const int bn = wg & 7;
  const int rowA0 = bm * 128;
  const int colB0 = bn * 128;

  floatx4 acc[2][4];
  #pragma unroll
  for (int m = 0; m < 2; m++)
    #pragma unroll
    for (int n = 0; n < 4; n++)
      acc[m][n] = (floatx4){0.f, 0.f, 0.f, 0.f};

  const int lr = lane & 15;
  const int lg = lane >> 4;
  const int sx = lane & 7;

  for (int k0 = 0; k0 < 256; k0 += 64) {
    stage_swz8(SM[0], Qb, 256, rowA0, k0, wave, lane);
    stage_swz8(SM[1], Wq, 256, colB0, k0, wave, lane);
    __syncthreads();
    #pragma unroll
    for (int ks = 0; ks < 2; ks++) {
      bhalf8 af[2], bfr[4];
      #pragma unroll
      for (int m = 0; m < 2; m++)
        af[m] = frag_ld(SM[0], wrow + m * 16 + lr, ks * 4 + lg, sx);
      #pragma unroll
      for (int n = 0; n < 4; n++)
        bfr[n] = frag_ld(SM[1], wcol + n * 16 + lr, ks * 4 + lg, sx);
      #pragma unroll
      for (int m = 0; m < 2; m++)
        #pragma unroll
        for (int n = 0; n < 4; n++)
          acc[m][n] = __builtin_amdgcn_mfma_f32_16x16x32_bf16(af[m], bfr[n], acc[m][n], 0, 0, 0);
    }
    __syncthreads();
  }

  ushort* ehi = (ushort*)SM[0];
  ushort* elo = ehi + 128 * 32;
  float*  ec  = (float*)SM[1];

  const int u_loc = (wave & 1) * 16 + lr;
  const int u     = bn * 32 + u_loc;
  const float4 b4 = biasp[u];
  #pragma unroll
  for (int m = 0; m < 2; m++) {
    #pragma unroll
    for (int rr = 0; rr < 4; rr++) {
      const int  rloc = wrow + m * 16 + lg * 4 + rr;
      const long row  = rowA0 + rloc;
      float pi = acc[m][0][rr] + b4.x;
      float pf = acc[m][1][rr] + b4.y;
      float pg = acc[m][2][rr] + b4.z;
      float po = acc[m][3][rr] + b4.w;
      uint2 pk;
      pk.x = (uint)f2b(pi) | ((uint)f2b(pf) << 16);
      pk.y = (uint)f2b(pg) | ((uint)f2b(po) << 16);
      Gq[row * NUNIT + u] = pk;
      float cn = sigmf(pi) * tanhfast(pg);
      ec[rloc * 32 + u_loc] = cn;
      float h = query[row * D_IN + u] + sigmf(po) * tanhfast(cn);
      ushort hh = f2b(h);
      ehi[rloc * 32 + u_loc] = hh;
      elo[rloc * 32 + u_loc] = f2b(h - b2f(hh));
    }
  }
  __syncthreads();
  const int u0 = bn * 32;
  {
    int row = tid >> 2, part = tid & 3;
    *(uint4*)(Hhi + (long)(rowA0 + row) * LDA_A + u0 + part * 8) = ((const uint4*)ehi)[tid];
    *(uint4*)(Hlo + (long)(rowA0 + row) * D_IN + u0 + part * 8) = ((const uint4*)elo)[tid];
  }
  #pragma unroll
  for (int i = tid; i < 1024; i += 512) {
    int row = i >> 3, part = i & 7;
    *(uint4*)(cbuf + (long)(rowA0 + row) * NUNIT + u0 + part * 4) = ((const uint4*)ec)[i];
  }
}

// ---------------------------------------------------------------------------
// Steps 1-3: gates = A @ Whh'^T + Gq; fused LSTM pointwise.
// Single-__syncthreads double-buffered K-loop (round-13 form, verified
// bit-exact at 469us; raw-s_barrier variant raced — reverted, frozen).
// ---------------------------------------------------------------------------
__global__ __launch_bounds__(512) void gemm_gates_fused(
    const ushort* __restrict__ A,
    const ushort* __restrict__ W,
    const uint2* __restrict__ Gq,
    float* __restrict__ cbuf,
    const float* __restrict__ query,
    ushort* __restrict__ Hhi,
    ushort* __restrict__ Hlo)
{
  __shared__ ushort SM[2][2][8192];

  const int tid  = threadIdx.x;
  const int lane = tid & 63;
  const int wave = tid >> 6;
  const int wrow = (wave >> 1) * 32;
  const int wcol = (wave & 1) * 64;
  const int wg = (blockIdx.x & 7) * (gridDim.x >> 3) + (blockIdx.x >> 3);
  const int bm = wg >> 3;
  const int bn = wg & 7;
  const int rowA0 = bm * 128;
  const int colB0 = bn * 128;

  floatx4 acc[2][4];
  #pragma unroll
  for (int m = 0; m < 2; m++)
    #pragma unroll
    for (int n = 0; n < 4; n++)
      acc[m][n] = (floatx4){0.f, 0.f, 0.f, 0.f};

  const int lr = lane & 15;
  const int lg = lane >> 4;
  const int sx = lane & 7;

  stage_swz8(SM[0][0], A, LDA_A, rowA0, 0, wave, lane);
  stage_swz8(SM[0][1], W, 512,   colB0, 0, wave, lane);
  __syncthreads();

  for (int t = 0; t < 8; t++) {
    const int cur = t & 1;
    if (t + 1 < 8) {
      stage_swz8(SM[cur ^ 1][0], A, LDA_A, rowA0, (t + 1) * 64, wave, lane);
      stage_swz8(SM[cur ^ 1][1], W, 512,   colB0, (t + 1) * 64, wave, lane);
    }
    const ushort* As = SM[cur][0];
    const ushort* Bs = SM[cur][1];
    #pragma unroll
    for (int ks = 0; ks < 2; ks++) {
      bhalf8 af[2], bfr[4];
      #pragma unroll
      for (int m = 0; m < 2; m++)
        af[m] = frag_ld(As, wrow + m * 16 + lr, ks * 4 + lg, sx);
      #pragma unroll
      for (int n = 0; n < 4; n++)
        bfr[n] = frag_ld(Bs, wcol + n * 16 + lr, ks * 4 + lg, sx);
      #pragma unroll
      for (int m = 0; m < 2; m++)
        #pragma unroll
        for (int n = 0; n < 4; n++)
          acc[m][n] = __builtin_amdgcn_mfma_f32_16x16x32_bf16(af[m], bfr[n], acc[m][n], 0, 0, 0);
    }
    __syncthreads();
  }

  ushort* ehi = (ushort*)SM[0][0];
  ushort* elo = ehi + 128 * 32;
  float*  ec  = (float*)SM[0][1];

  const int u_loc = (wave & 1) * 16 + lr;
  const int u     = bn * 32 + u_loc;
  #pragma unroll
  for (int m = 0; m < 2; m++) {
    #pragma unroll
    for (int rr = 0; rr < 4; rr++) {
      const int  rloc = wrow + m * 16 + lg * 4 + rr;
      const long row  = rowA0 + rloc;
      uint2 pk = Gq[row * NUNIT + u];
      float pi = acc[m][0][rr] + b2f((ushort)(pk.x & 0xffff));
      float pf = acc[m][1][rr] + b2f((ushort)(pk.x >> 16));
      float pg = acc[m][2][rr] + b2f((ushort)(pk.y & 0xffff));
      float po = acc[m][3][rr] + b2f((ushort)(pk.y >> 16));
      float cn = sigmf(pf) * cbuf[row * NUNIT + u] + sigmf(pi) * tanhfast(pg);
      ec[rloc * 32 + u_loc] = cn;
      float h = query[row * D_IN + u] + sigmf(po) * tanhfast(cn);
      ushort hh = f2b(h);
      ehi[rloc * 32 + u_loc] = hh;
      elo[rloc * 32 + u_loc] = f2b(h - b2f(hh));
    }
  }
  __syncthreads();
  const int u0 = bn * 32;
  {
    int row = tid >> 2, part = tid & 3;
    *(uint4*)(Hhi + (long)(rowA0 + row) * LDA_A + u0 + part * 8) = ((const uint4*)ehi)[tid];
    *(uint4*)(Hlo + (long)(rowA0 + row) * D_IN + u0 + part * 8) = ((const uint4*)elo)[tid];
  }
  #pragma unroll
  for (int i = tid; i < 1024; i += 512) {
    int row = i >> 3, part = i & 7;
    *(uint4*)(cbuf + (long)(rowA0 + row) * NUNIT + u0 + part * 4) = ((const uint4*)ec)[i];
  }
}

// ---------------------------------------------------------------------------
// Split-precision scores GEMM -> d_out fp32 (FINAL step only; round-9 form).
// ---------------------------------------------------------------------------
__global__ __launch_bounds__(256) void gemm_scores(
    const ushort* __restrict__ Ahi,
    const ushort* __restrict__ Alo,
    const ushort* __restrict__ Bhi, const ushort* __restrict__ Blo,
    float* __restrict__ C)
{
  __shared__ ushort AsH[128 * 64];
  __shared__ ushort AsL[128 * 64];
  __shared__ ushort BsH[128 * 64];
  __shared__ ushort BsL[128 * 64];

  const int tid  = threadIdx.x;
  const int lane = tid & 63;
  const int wave = tid >> 6;
  const int wr = (wave >> 1) * 64;
  const int wc = (wave & 1) * 64;
  const int wg = (blockIdx.x & 7) * (gridDim.x >> 3) + (blockIdx.x >> 3);
  const int bm = wg >> 2;
  const int bn = wg & 3;
  const int rowA0 = bm * 128;
  const int rowB0 = bn * 128;

  floatx4 acc[4][4];
  #pragma unroll
  for (int m = 0; m < 4; m++)
    #pragma unroll
    for (int n = 0; n < 4; n++)
      acc[m][n] = (floatx4){0.f, 0.f, 0.f, 0.f};

  const int lr = lane & 15;
  const int lg = lane >> 4;
  const int sx = lane & 7;

  for (int k0 = 0; k0 < D_IN; k0 += 64) {
    stage_swz4(AsH, Ahi, LDA_A, rowA0, k0, wave, lane);
    stage_swz4(AsL, Alo, D_IN,  rowA0, k0, wave, lane);
    stage_swz4(BsH, Bhi, D_IN,  rowB0, k0, wave, lane);
    stage_swz4(BsL, Blo, D_IN,  rowB0, k0, wave, lane);
    __syncthreads();
    #pragma unroll
    for (int ks = 0; ks < 2; ks++) {
      bhalf8 afh[4], afl[4], bfh[4], bfl[4];
      #pragma unroll
      for (int m = 0; m < 4; m++) {
        afh[m] = frag_ld(AsH, wr + m * 16 + lr, ks * 4 + lg, sx);
        afl[m] = frag_ld(AsL, wr + m * 16 + lr, ks * 4 + lg, sx);
      }
      #pragma unroll
      for (int n = 0; n < 4; n++) {
        bfh[n] = frag_ld(BsH, wc + n * 16 + lr, ks * 4 + lg, sx);
        bfl[n] = frag_ld(BsL, wc + n * 16 + lr, ks * 4 + lg, sx);
      }
      #pragma unroll
      for (int m = 0; m < 4; m++)
        #pragma unroll
        for (int n = 0; n < 4; n++) {
          acc[m][n] = __builtin_amdgcn_mfma_f32_16x16x32_bf16(afl[m], bfh[n], acc[m][n], 0, 0, 0);
          acc[m][n] = __builtin_amdgcn_mfma_f32_16x16x32_bf16(afh[m], bfl[n], acc[m][n], 0, 0, 0);
          acc[m][n] = __builtin_amdgcn_mfma_f32_16x16x32_bf16(afh[m], bfh[n], acc[m][n], 0, 0, 0);
        }
    }
    __syncthreads();
  }

  #pragma unroll
  for (int m = 0; m < 4; m++)
    #pragma unroll
    for (int n = 0; n < 4; n++)
      #pragma unroll
      for (int r = 0; r < 4; r++) {
        int row = rowA0 + wr + m * 16 + lg * 4 + r;
        int col = rowB0 + wc + n * 16 + lr;
        C[(long)row * NSUP + col] = acc[m][n][r];
      }
}

// ---------------------------------------------------------------------------
// Fused scores + softmax + PV for steps 0-2 (round-14 form, verified 66us /
// total 469us; M=64, 128 KB LDS). THIS ROUND: phase-3 STb staging
// double-buffered with the verified r13 single-__syncthreads pattern
// (Bpv[2] fills Breg; elr overlays Bpv0 after the final barrier).
// Operand bytes & MFMA order unchanged -> bit-identical output.
// ---------------------------------------------------------------------------
__global__ __launch_bounds__(512) void k_sspv(
    const ushort* __restrict__ Ahi,   // Abuf + hoff (ld 768)
    const ushort* __restrict__ Alo,   // Hlo (ld 256)
    const ushort* __restrict__ Shi,   // [512][256]
    const ushort* __restrict__ Slo,   // [512][256]
    const ushort* __restrict__ STb,   // [256][512]
    ushort* __restrict__ Cv)          // Abuf + 256 (ldc LDA_A)
{
  __shared__ ushort SMEM[65536];      // 128 KB
  ushort* Areg = SMEM;                // Ahi 4x[64][64] @0, Alo @16384; later P[64][512]
  ushort* Breg = SMEM + 32768;        // S chunk [512][64]; later scf; later Bpv[2]/elr

  const int tid  = threadIdx.x;
  const int lane = tid & 63;
  const int wave = tid >> 6;
  const int wg = (blockIdx.x & 7) * (gridDim.x >> 3) + (blockIdx.x >> 3);
  const long rowA0 = (long)wg * 64;

  const int lr = lane & 15;
  const int lg = lane >> 4;
  const int sx = lane & 7;

  // ---- stage A (hi: waves 0-3 / lo: waves 4-7; each wave one 64-K chunk) ----
  {
    const ushort* asrc = (wave < 4) ? Ahi : Alo;
    const int ald = (wave < 4) ? LDA_A : D_IN;
    ushort* adst = Areg + (wave >> 2) * 16384 + (wave & 3) * 4096;
    const int ak0 = (wave & 3) * 64;
    #pragma unroll
    for (int q = 0; q < 8; q++)
      stage_rows8(adst, asrc, ald, rowA0, q * 8, ak0, lane);
  }
  // first Shi chunk (kc=0)
  #pragma unroll
  for (int q = 0; q < 8; q++)
    stage_rows8(Breg, Shi, D_IN, 0, wave * 64 + q * 8, 0, lane);
  __syncthreads();

  floatx4 acc[4][4];
  #pragma unroll
  for (int m = 0; m < 4; m++)
    #pragma unroll
    for (int n = 0; n < 4; n++)
      acc[m][n] = (floatx4){0.f, 0.f, 0.f, 0.f};

  for (int kc = 0; kc < 4; kc++) {
    const ushort* Ah = Areg + kc * 4096;
    const ushort* Al = Areg + 16384 + kc * 4096;
    // hi pass: afl*bfh + afh*bfh
    #pragma unroll
    for (int ks = 0; ks < 2; ks++) {
      bhalf8 afh[4], afl[4], bfh[4];
      #pragma unroll
      for (int m = 0; m < 4; m++) {
        afh[m] = frag_ld(Ah, m * 16 + lr, ks * 4 + lg, sx);
        afl[m] = frag_ld(Al, m * 16 + lr, ks * 4 + lg, sx);
      }
      #pragma unroll
      for (int n = 0; n < 4; n++)
        bfh[n] = frag_ld(Breg, wave * 64 + n * 16 + lr, ks * 4 + lg, sx);
      #pragma unroll
      for (int m = 0; m < 4; m++)
        #pragma unroll
        for (int n = 0; n < 4; n++) {
          acc[m][n] = __builtin_amdgcn_mfma_f32_16x16x32_bf16(afl[m], bfh[n], acc[m][n], 0, 0, 0);
          acc[m][n] = __builtin_amdgcn_mfma_f32_16x16x32_bf16(afh[m], bfh[n], acc[m][n], 0, 0, 0);
        }
    }
    __syncthreads();
    // stage Slo chunk into the same buffer
    #pragma unroll
    for (int q = 0; q < 8; q++)
      stage_rows8(Breg, Slo, D_IN, 0, wave * 64 + q * 8, kc * 64, lane);
    __syncthreads();
    // lo pass: afh*bfl
    #pragma unroll
    for (int ks = 0; ks < 2; ks++) {
      bhalf8 afh[4], bfl[4];
      #pragma unroll
      for (int m = 0; m < 4; m++)
        afh[m] = frag_ld(Ah, m * 16 + lr, ks * 4 + lg, sx);
      #pragma unroll
      for (int n = 0; n < 4; n++)
        bfl[n] = frag_ld(Breg, wave * 64 + n * 16 + lr, ks * 4 + lg, sx);
      #pragma unroll
      for (int m = 0; m < 4; m++)
        #pragma unroll
        for (int n = 0; n < 4; n++)
          acc[m][n] = __builtin_amdgcn_mfma_f32_16x16x32_bf16(afh[m], bfl[n], acc[m][n], 0, 0, 0);
    }
    __syncthreads();
    if (kc < 3) {
      #pragma unroll
      for (int q = 0; q < 8; q++)
        stage_rows8(Breg, Shi, D_IN, 0, wave * 64 + q * 8, (kc + 1) * 64, lane);
      __syncthreads();
    }
  }

  // ---- phase 2: scores -> LDS fp32 (two 32-row halves) + softmax -> P ----
  float*  scf = (float*)Breg;         // [32][512] fp32 = 64 KB
  ushort* Ps  = Areg;                 // [64][512] bf16 swizzled (A region dead)
  const int po  = (lane >> 1) & 7;
  const int ph4 = (lane & 1) * 4;
  const int pg0 = lane >> 4;

  #pragma unroll
  for (int half = 0; half < 2; half++) {
    #pragma unroll
    for (int mm = 0; mm < 2; mm++) {
      const int m = half * 2 + mm;
      #pragma unroll
      for (int n = 0; n < 4; n++)
        #pragma unroll
        for (int r = 0; r < 4; r++)
          scf[(mm * 16 + lg * 4 + r) * 512 + wave * 64 + n * 16 + lr] = acc[m][n][r];
    }
    __syncthreads();
    #pragma unroll
    for (int j = 0; j < 4; j++) {
      const int rl = wave * 4 + j;          // row within half (0..31)
      const int r  = half * 32 + rl;        // true local row (0..63)
      const float4* sp = reinterpret_cast<const float4*>(scf + rl * 512);
      float4 v0 = sp[lane];
      float4 v1 = sp[64 + lane];
      float m = fmaxf(fmaxf(fmaxf(v0.x, v0.y), fmaxf(v0.z, v0.w)),
                      fmaxf(fmaxf(v1.x, v1.y), fmaxf(v1.z, v1.w)));
      #pragma unroll
      for (int off = 32; off >= 1; off >>= 1) m = fmaxf(m, __shfl_xor(m, off));
      float e0 = __expf(v0.x - m), e1 = __expf(v0.y - m), e2 = __expf(v0.z - m), e3 = __expf(v0.w - m);
      float e4 = __expf(v1.x - m), e5 = __expf(v1.y - m), e6 = __expf(v1.z - m), e7 = __expf(v1.w - m);
      float s = e0 + e1 + e2 + e3 + e4 + e5 + e6 + e7;
      #pragma unroll
      for (int off = 32; off >= 1; off >>= 1) s += __shfl_xor(s, off);
      float inv = 1.0f / s;
      uint2 p0, p1;
      p0.x = (uint)f2b(e0 * inv) | ((uint)f2b(e1 * inv) << 16);
      p0.y = (uint)f2b(e2 * inv) | ((uint)f2b(e3 * inv) << 16);
      p1.x = (uint)f2b(e4 * inv) | ((uint)f2b(e5 * inv) << 16);
      p1.y = (uint)f2b(e6 * inv) | ((uint)f2b(e7 * inv) << 16);
      const int os = ((po ^ (r & 7)) << 3) + ph4;
      *(uint2*)&Ps[r * 512 + (pg0    ) * 64 + os] = p0;
      *(uint2*)&Ps[r * 512 + (pg0 + 4) * 64 + os] = p1;
    }
    __syncthreads();
  }

  // ---- phase 3: r = P @ STb^T, STb chunks double-buffered (r13 pattern) ----
  floatx4 pacc[4][2];
  #pragma unroll
  for (int m = 0; m < 4; m++)
    #pragma unroll
    for (int n = 0; n < 2; n++)
      pacc[m][n] = (floatx4){0.f, 0.f, 0.f, 0.f};

  ushort* Bpv0 = Breg;                // [256][64] chunk (32 KB)
  ushort* Bpv1 = Breg + 16384;        // second buffer (32 KB)
  #pragma unroll
  for (int q = 0; q < 4; q++)
    stage_rows8(Bpv0, STb, NSUP, 0, wave * 32 + q * 8, 0, lane);
  __syncthreads();
  for (int kc = 0; kc < 8; kc++) {
    ushort* Bcur = (kc & 1) ? Bpv1 : Bpv0;
    ushort* Bnxt = (kc & 1) ? Bpv0 : Bpv1;
    if (kc + 1 < 8) {
      #pragma unroll
      for (int q = 0; q < 4; q++)
        stage_rows8(Bnxt, STb, NSUP, 0, wave * 32 + q * 8, (kc + 1) * 64, lane);
    }
    #pragma unroll
    for (int ks = 0; ks < 2; ks++) {
      bhalf8 af[4], bfr[2];
      #pragma unroll
      for (int m = 0; m < 4; m++)
        af[m] = frag_ld512(Ps, m * 16 + lr, kc, ks * 4 + lg, sx);
      #pragma unroll
      for (int n = 0; n < 2; n++)
        bfr[n] = frag_ld(Bcur, wave * 32 + n * 16 + lr, ks * 4 + lg, sx);
      #pragma unroll
      for (int m = 0; m < 4; m++)
        #pragma unroll
        for (int n = 0; n < 2; n++)
          pacc[m][n] = __builtin_amdgcn_mfma_f32_16x16x32_bf16(af[m], bfr[n], pacc[m][n], 0, 0, 0);
    }
    __syncthreads();
  }

  // ---- epilogue: r [64][256] bf16 via LDS (overlays Bpv0), coalesced ----
  ushort* elr = Breg;                 // 32 KB; all Bpv reads done (final sync)
  #pragma unroll
  for (int m = 0; m < 4; m++)
    #pragma unroll
    for (int n = 0; n < 2; n++)
      #pragma unroll
      for (int r = 0; r < 4; r++)
        elr[(m * 16 + lg * 4 + r) * 256 + wave * 32 + n * 16 + lr] = f2b(pacc[m][n][r]);
  __syncthreads();
  #pragma unroll
  for (int i = tid; i < 2048; i += 512) {
    int row = i >> 5, part = i & 31;
    *(uint4*)(Cv + (rowA0 + row) * LDA_A + part * 8) = ((const uint4*)elr)[i];
  }
}

// ---------------------------------------------------------------------------
// Build permuted live-unit weights + bias + S hi/lo + S^T. (unchanged)
// ---------------------------------------------------------------------------
__global__ __launch_bounds__(256) void k_build(
    const float* __restrict__ Wih, const float* __restrict__ Whh,
    const float* __restrict__ bih, const float* __restrict__ bhh,
    const float* __restrict__ S,
    ushort* __restrict__ We, ushort* __restrict__ Wo, ushort* __restrict__ Wq,
    float4* __restrict__ biasp,
    ushort* __restrict__ Shi, ushort* __restrict__ Slo,
    ushort* __restrict__ STb)
{
  int t = blockIdx.x * 256 + threadIdx.x;
  if (t < GN * 512) {
    int c = t >> 9, k = t & 511;
    int unit = (c >> 6) * 16 + (c & 15);
    int gate = (c >> 4) & 3;
    long srow = (long)(gate * 512 + unit);
    We[(long)c * 512 + k] = f2b(Whh[srow * 512 + k]);
    int ko = (k < 256) ? (256 + k) : (k - 256);
    Wo[(long)c * 512 + k] = f2b(Whh[srow * 512 + ko]);
    if (k < 256) Wq[(long)c * 256 + k] = f2b(Wih[srow * 256 + k]);
  }
  if (t < NUNIT) {
    biasp[t] = make_float4(bih[t] + bhh[t],
                           bih[512 + t] + bhh[512 + t],
                           bih[1024 + t] + bhh[1024 + t],
                           bih[1536 + t] + bhh[1536 + t]);
  }
  if (t < NSUP * D_IN) {
    float v = S[t];
    ushort hv = f2b(v);
    Shi[t] = hv;
    Slo[t] = f2b(v - b2f(hv));
    int s = t >> 8, d = t & 255;
    STb[(long)d * NSUP + s] = hv;
  }
}

// bf16 copy of query (GEMM operand only; epilogues use fp32 query).
__global__ __launch_bounds__(256) void k_initq(
    const float* __restrict__ query, ushort* __restrict__ Qb)
{
  long t = (long)blockIdx.x * 256 + threadIdx.x;
  Qb[t] = f2b(query[t]);
}

// ---------------------------------------------------------------------------
extern "C" void kernel_launch(void* const* d_in, const int* in_sizes, int n_in,
                              void* d_out, int out_size, void* d_ws, size_t ws_size,
                              hipStream_t stream)
{
  const float* support_mean = (const float*)d_in[0];
  const float* query_mean   = (const float*)d_in[2];
  const float* W_ih = (const float*)d_in[4];
  const float* W_hh = (const float*)d_in[5];
  const float* b_ih = (const float*)d_in[6];
  const float* b_hh = (const float*)d_in[7];
  float* out = (float*)d_out;

  char* ws = (char*)d_ws;
  size_t off = 0;
  auto alloc = [&](size_t bytes) {
    void* p = ws + off;
    off += (bytes + 255) & ~(size_t)255;
    return p;
  };
  ushort* Abuf  = (ushort*)alloc((size_t)BATCH_N * LDA_A * 2);  // 50.3 MB
  ushort* Qb    = (ushort*)alloc((size_t)BATCH_N * D_IN * 2);   // 16.8 MB
  ushort* We    = (ushort*)alloc((size_t)GN * 512 * 2);         // 1.05 MB
  ushort* Wo    = (ushort*)alloc((size_t)GN * 512 * 2);         // 1.05 MB
  ushort* Wq    = (ushort*)alloc((size_t)GN * 256 * 2);         // 0.52 MB
  float4* biasp = (float4*)alloc((size_t)NUNIT * 16);
  ushort* Shi   = (ushort*)alloc((size_t)NSUP * D_IN * 2);
  ushort* Slo   = (ushort*)alloc((size_t)NSUP * D_IN * 2);
  ushort* STb   = (ushort*)alloc((size_t)D_IN * NSUP * 2);
  float*  cbuf  = (float*) alloc((size_t)BATCH_N * NUNIT * 4);  // 33.6 MB
  ushort* Hlo   = (ushort*)alloc((size_t)BATCH_N * D_IN * 2);   // 16.8 MB
  uint2*  Gq    = (uint2*) alloc((size_t)BATCH_N * NUNIT * 8);  // 67.1 MB
  if (off > ws_size) return;  // total ~189 MB; >=255 MB proven available

  hipLaunchKernelGGL(k_build, dim3((GN * 512) / 256), dim3(256), 0, stream,
                     W_ih, W_hh, b_ih, b_hh, support_mean,
                     We, Wo, Wq, biasp, Shi, Slo, STb);
  hipLaunchKernelGGL(k_initq, dim3((BATCH_N * D_IN) / 256), dim3(256), 0, stream,
                     query_mean, Qb);

  // Gq = q@Wq^T + b (shared by all steps) + step-0 pointwise -> h_a, c.
  hipLaunchKernelGGL(gemm_gq_fused,
                     dim3((BATCH_N / 128) * (GN / 128)), dim3(512), 0, stream,
                     Qb, Wq, biasp, Gq, cbuf, query_mean, Abuf + 0, Hlo);

  // steps 0-2: fused scores+softmax+PV (no d_out traffic), then next gates.
  for (int s = 0; s < 3; s++) {
    const int hoff = (s & 1) * 512;   // h slot of step s
    hipLaunchKernelGGL(k_sspv, dim3(BATCH_N / 64), dim3(512), 0, stream,
                       Abuf + hoff, Hlo, Shi, Slo, STb, Abuf + 256);
    const int aoff = ((s + 1) == 2) ? 256 : 0;
    const ushort* Wnext = ((s + 1) == 2) ? Wo : We;
    hipLaunchKernelGGL(gemm_gates_fused,
                       dim3((BATCH_N / 128) * (GN / 128)), dim3(512), 0, stream,
                       Abuf + aoff, Wnext, Gq, cbuf, query_mean,
                       Abuf + ((s + 1) & 1) * 512, Hlo);
  }
  // step 3: final scores -> d_out (h in h_b slot, hoff 512)
  hipLaunchKernelGGL(gemm_scores,
                     dim3((BATCH_N / 128) * (NSUP / 128)), dim3(256), 0, stream,
                     Abuf + 512, Hlo, Shi, Slo, out);
}

// Round 18
// 437.520 us; speedup vs baseline: 1.1018x; 1.0425x over previous
//
#include <hip/hip_runtime.h>

typedef unsigned int uint;
typedef unsigned short ushort;
typedef __attribute__((ext_vector_type(8))) short bhalf8;
typedef __attribute__((ext_vector_type(4))) float floatx4;

#define D_IN 256
#define NUNIT 256     // live hidden units (256:512 dead: h_new[:,256:] never read)
#define GN 1024       // gates N = 4 gates x 256 units
#define NSUP 512
#define BATCH_N 32768
#define LDA_A 768     // A_cat: [h_a(0:256) | r(256:512) | h_b(512:768)]

__device__ __forceinline__ ushort f2b(float f){
  union { float f; uint u; } x; x.f = f;
  uint r = (x.u + 0x7fffu + ((x.u >> 16) & 1u)) >> 16;
  return (ushort)r;
}
__device__ __forceinline__ float b2f(ushort u){
  union { uint u; float f; } x; x.u = ((uint)u) << 16;
  return x.f;
}
__device__ __forceinline__ float sigmf(float x){ return 1.0f / (1.0f + __expf(-x)); }
__device__ __forceinline__ float tanhfast(float x){ return 1.0f - 2.0f / (1.0f + __expf(2.0f * x)); }

// ---------------------------------------------------------------------------
// global->LDS staging with SOURCE PRE-SWIZZLE (m173): LDS linear; lane fetches
// global octet (lane&7)^(lane>>3) so LDS[R][o] = G[R][o ^ (R&7)]; reads apply
// the same XOR (frag_ld). Verified round 5: bank conflicts 3.8e7 -> 0.
// ---------------------------------------------------------------------------
__device__ __forceinline__ void stage_rows8(
    ushort* lds_base, const ushort* __restrict__ g, int ld,
    long grow0, int lrow0, int k0, int lane)
{
  const int rsub = lane >> 3;
  const int oct  = (lane & 7) ^ rsub;
  const ushort* gp = g + (grow0 + lrow0 + rsub) * ld + k0 + (oct << 3);
  ushort* lp = lds_base + lrow0 * 64;
  __builtin_amdgcn_global_load_lds(
      (const __attribute__((address_space(1))) void*)gp,
      (__attribute__((address_space(3))) void*)lp, 16, 0, 0);
}

__device__ __forceinline__ void stage_swz4(
    ushort* lds, const ushort* __restrict__ g, int ld, int row0, int k0,
    int wave, int lane)
{
  #pragma unroll
  for (int q = 0; q < 4; q++)
    stage_rows8(lds, g, ld, row0, wave * 32 + q * 8, k0, lane);
}

__device__ __forceinline__ void stage_swz8(
    ushort* lds, const ushort* __restrict__ g, int ld, int row0, int k0,
    int wave, int lane)
{
  #pragma unroll
  for (int q = 0; q < 2; q++)
    stage_rows8(lds, g, ld, row0, wave * 16 + q * 8, k0, lane);
}

__device__ __forceinline__ bhalf8 frag_ld(const ushort* lds, int R, int O, int sx)
{
  return *reinterpret_cast<const bhalf8*>(&lds[R * 64 + (((O ^ sx) & 7) << 3)]);
}

// 512-col-wide swizzled LDS tile read: col group g (64 cols), octet O in group.
__device__ __forceinline__ bhalf8 frag_ld512(const ushort* lds, int R, int g, int O, int sx)
{
  return *reinterpret_cast<const bhalf8*>(&lds[R * 512 + g * 64 + (((O ^ sx) & 7) << 3)]);
}

// ---------------------------------------------------------------------------
// Gq = q @ Wq^T + bias (K=256, N=1024 permuted) -> packed bf16 uint2 {i|f,g|o}.
// Epilogue also runs step-0 pointwise (fp32 query).
// THIS ROUND: single-__syncthreads double-buffered K-loop (r13/r17 verified
// pattern; bit-identical MFMA order/operands). 64 KB LDS.
// ---------------------------------------------------------------------------
__global__ __launch_bounds__(512) void gemm_gq_fused(
    const ushort* __restrict__ Qb,
    const ushort* __restrict__ Wq,
    const float4* __restrict__ biasp,
    uint2* __restrict__ Gq,
    float* __restrict__ cbuf,
    const float* __restrict__ query,
    ushort* __restrict__ Hhi,
    ushort* __restrict__ Hlo)
{
  __shared__ ushort SM[2][2][8192];    // [buf][A/B][128x64] = 64 KB

  const int tid  = threadIdx.x;
  const int lane = tid & 63;
  const int wave = tid >> 6;
  const int wrow = (wave >> 1) * 32;
  const int wcol = (wave & 1) * 64;
  const int wg = (blockIdx.x & 7) * (gridDim.x >> 3) + (blockIdx.x >> 3);
  const int bm = wg >> 3;
  const int bn = wg & 7;
  const int rowA0 = bm * 128;
  const int colB0 = bn * 128;

  floatx4 acc[2][4];
  #pragma unroll
  for (int m = 0; m < 2; m++)
    #pragma unroll
    for (int n = 0; n < 4; n++)
      acc[m][n] = (floatx4){0.f, 0.f, 0.f, 0.f};

  const int lr = lane & 15;
  const int lg = lane >> 4;
  const int sx = lane & 7;

  stage_swz8(SM[0][0], Qb, 256, rowA0, 0, wave, lane);
  stage_swz8(SM[0][1], Wq, 256, colB0, 0, wave, lane);
  __syncthreads();

  for (int t = 0; t < 4; t++) {
    const int cur = t & 1;
    if (t + 1 < 4) {
      stage_swz8(SM[cur ^ 1][0], Qb, 256, rowA0, (t + 1) * 64, wave, lane);
      stage_swz8(SM[cur ^ 1][1], Wq, 256, colB0, (t + 1) * 64, wave, lane);
    }
    const ushort* As = SM[cur][0];
    const ushort* Bs = SM[cur][1];
    #pragma unroll
    for (int ks = 0; ks < 2; ks++) {
      bhalf8 af[2], bfr[4];
      #pragma unroll
      for (int m = 0; m < 2; m++)
        af[m] = frag_ld(As, wrow + m * 16 + lr, ks * 4 + lg, sx);
      #pragma unroll
      for (int n = 0; n < 4; n++)
        bfr[n] = frag_ld(Bs, wcol + n * 16 + lr, ks * 4 + lg, sx);
      #pragma unroll
      for (int m = 0; m < 2; m++)
        #pragma unroll
        for (int n = 0; n < 4; n++)
          acc[m][n] = __builtin_amdgcn_mfma_f32_16x16x32_bf16(af[m], bfr[n], acc[m][n], 0, 0, 0);
    }
    __syncthreads();
  }

  ushort* ehi = (ushort*)SM[0][0];
  ushort* elo = ehi + 128 * 32;
  float*  ec  = (float*)SM[0][1];

  const int u_loc = (wave & 1) * 16 + lr;
  const int u     = bn * 32 + u_loc;
  const float4 b4 = biasp[u];
  #pragma unroll
  for (int m = 0; m < 2; m++) {
    #pragma unroll
    for (int rr = 0; rr < 4; rr++) {
      const int  rloc = wrow + m * 16 + lg * 4 + rr;
      const long row  = rowA0 + rloc;
      float pi = acc[m][0][rr] + b4.x;
      float pf = acc[m][1][rr] + b4.y;
      float pg = acc[m][2][rr] + b4.z;
      float po = acc[m][3][rr] + b4.w;
      uint2 pk;
      pk.x = (uint)f2b(pi) | ((uint)f2b(pf) << 16);
      pk.y = (uint)f2b(pg) | ((uint)f2b(po) << 16);
      Gq[row * NUNIT + u] = pk;
      float cn = sigmf(pi) * tanhfast(pg);
      ec[rloc * 32 + u_loc] = cn;
      float h = query[row * D_IN + u] + sigmf(po) * tanhfast(cn);
      ushort hh = f2b(h);
      ehi[rloc * 32 + u_loc] = hh;
      elo[rloc * 32 + u_loc] = f2b(h - b2f(hh));
    }
  }
  __syncthreads();
  const int u0 = bn * 32;
  {
    int row = tid >> 2, part = tid & 3;
    *(uint4*)(Hhi + (long)(rowA0 + row) * LDA_A + u0 + part * 8) = ((const uint4*)ehi)[tid];
    *(uint4*)(Hlo + (long)(rowA0 + row) * D_IN + u0 + part * 8) = ((const uint4*)elo)[tid];
  }
  #pragma unroll
  for (int i = tid; i < 1024; i += 512) {
    int row = i >> 3, part = i & 7;
    *(uint4*)(cbuf + (long)(rowA0 + row) * NUNIT + u0 + part * 4) = ((const uint4*)ec)[i];
  }
}

// ---------------------------------------------------------------------------
// Steps 1-3: gates = A @ Whh'^T + Gq; fused LSTM pointwise.
// Single-__syncthreads double-buffered K-loop (round-13/17 form, verified
// bit-exact at 456us; frozen).
// ---------------------------------------------------------------------------
__global__ __launch_bounds__(512) void gemm_gates_fused(
    const ushort* __restrict__ A,
    const ushort* __restrict__ W,
    const uint2* __restrict__ Gq,
    float* __restrict__ cbuf,
    const float* __restrict__ query,
    ushort* __restrict__ Hhi,
    ushort* __restrict__ Hlo)
{
  __shared__ ushort SM[2][2][8192];

  const int tid  = threadIdx.x;
  const int lane = tid & 63;
  const int wave = tid >> 6;
  const int wrow = (wave >> 1) * 32;
  const int wcol = (wave & 1) * 64;
  const int wg = (blockIdx.x & 7) * (gridDim.x >> 3) + (blockIdx.x >> 3);
  const int bm = wg >> 3;
  const int bn = wg & 7;
  const int rowA0 = bm * 128;
  const int colB0 = bn * 128;

  floatx4 acc[2][4];
  #pragma unroll
  for (int m = 0; m < 2; m++)
    #pragma unroll
    for (int n = 0; n < 4; n++)
      acc[m][n] = (floatx4){0.f, 0.f, 0.f, 0.f};

  const int lr = lane & 15;
  const int lg = lane >> 4;
  const int sx = lane & 7;

  stage_swz8(SM[0][0], A, LDA_A, rowA0, 0, wave, lane);
  stage_swz8(SM[0][1], W, 512,   colB0, 0, wave, lane);
  __syncthreads();

  for (int t = 0; t < 8; t++) {
    const int cur = t & 1;
    if (t + 1 < 8) {
      stage_swz8(SM[cur ^ 1][0], A, LDA_A, rowA0, (t + 1) * 64, wave, lane);
      stage_swz8(SM[cur ^ 1][1], W, 512,   colB0, (t + 1) * 64, wave, lane);
    }
    const ushort* As = SM[cur][0];
    const ushort* Bs = SM[cur][1];
    #pragma unroll
    for (int ks = 0; ks < 2; ks++) {
      bhalf8 af[2], bfr[4];
      #pragma unroll
      for (int m = 0; m < 2; m++)
        af[m] = frag_ld(As, wrow + m * 16 + lr, ks * 4 + lg, sx);
      #pragma unroll
      for (int n = 0; n < 4; n++)
        bfr[n] = frag_ld(Bs, wcol + n * 16 + lr, ks * 4 + lg, sx);
      #pragma unroll
      for (int m = 0; m < 2; m++)
        #pragma unroll
        for (int n = 0; n < 4; n++)
          acc[m][n] = __builtin_amdgcn_mfma_f32_16x16x32_bf16(af[m], bfr[n], acc[m][n], 0, 0, 0);
    }
    __syncthreads();
  }

  ushort* ehi = (ushort*)SM[0][0];
  ushort* elo = ehi + 128 * 32;
  float*  ec  = (float*)SM[0][1];

  const int u_loc = (wave & 1) * 16 + lr;
  const int u     = bn * 32 + u_loc;
  #pragma unroll
  for (int m = 0; m < 2; m++) {
    #pragma unroll
    for (int rr = 0; rr < 4; rr++) {
      const int  rloc = wrow + m * 16 + lg * 4 + rr;
      const long row  = rowA0 + rloc;
      uint2 pk = Gq[row * NUNIT + u];
      float pi = acc[m][0][rr] + b2f((ushort)(pk.x & 0xffff));
      float pf = acc[m][1][rr] + b2f((ushort)(pk.x >> 16));
      float pg = acc[m][2][rr] + b2f((ushort)(pk.y & 0xffff));
      float po = acc[m][3][rr] + b2f((ushort)(pk.y >> 16));
      float cn = sigmf(pf) * cbuf[row * NUNIT + u] + sigmf(pi) * tanhfast(pg);
      ec[rloc * 32 + u_loc] = cn;
      float h = query[row * D_IN + u] + sigmf(po) * tanhfast(cn);
      ushort hh = f2b(h);
      ehi[rloc * 32 + u_loc] = hh;
      elo[rloc * 32 + u_loc] = f2b(h - b2f(hh));
    }
  }
  __syncthreads();
  const int u0 = bn * 32;
  {
    int row = tid >> 2, part = tid & 3;
    *(uint4*)(Hhi + (long)(rowA0 + row) * LDA_A + u0 + part * 8) = ((const uint4*)ehi)[tid];
    *(uint4*)(Hlo + (long)(rowA0 + row) * D_IN + u0 + part * 8) = ((const uint4*)elo)[tid];
  }
  #pragma unroll
  for (int i = tid; i < 1024; i += 512) {
    int row = i >> 3, part = i & 7;
    *(uint4*)(cbuf + (long)(rowA0 + row) * NUNIT + u0 + part * 4) = ((const uint4*)ec)[i];
  }
}

// ---------------------------------------------------------------------------
// Split-precision scores GEMM -> d_out fp32 (FINAL step only; round-9 form).
// ---------------------------------------------------------------------------
__global__ __launch_bounds__(256) void gemm_scores(
    const ushort* __restrict__ Ahi,
    const ushort* __restrict__ Alo,
    const ushort* __restrict__ Bhi, const ushort* __restrict__ Blo,
    float* __restrict__ C)
{
  __shared__ ushort AsH[128 * 64];
  __shared__ ushort AsL[128 * 64];
  __shared__ ushort BsH[128 * 64];
  __shared__ ushort BsL[128 * 64];

  const int tid  = threadIdx.x;
  const int lane = tid & 63;
  const int wave = tid >> 6;
  const int wr = (wave >> 1) * 64;
  const int wc = (wave & 1) * 64;
  const int wg = (blockIdx.x & 7) * (gridDim.x >> 3) + (blockIdx.x >> 3);
  const int bm = wg >> 2;
  const int bn = wg & 3;
  const int rowA0 = bm * 128;
  const int rowB0 = bn * 128;

  floatx4 acc[4][4];
  #pragma unroll
  for (int m = 0; m < 4; m++)
    #pragma unroll
    for (int n = 0; n < 4; n++)
      acc[m][n] = (floatx4){0.f, 0.f, 0.f, 0.f};

  const int lr = lane & 15;
  const int lg = lane >> 4;
  const int sx = lane & 7;

  for (int k0 = 0; k0 < D_IN; k0 += 64) {
    stage_swz4(AsH, Ahi, LDA_A, rowA0, k0, wave, lane);
    stage_swz4(AsL, Alo, D_IN,  rowA0, k0, wave, lane);
    stage_swz4(BsH, Bhi, D_IN,  rowB0, k0, wave, lane);
    stage_swz4(BsL, Blo, D_IN,  rowB0, k0, wave, lane);
    __syncthreads();
    #pragma unroll
    for (int ks = 0; ks < 2; ks++) {
      bhalf8 afh[4], afl[4], bfh[4], bfl[4];
      #pragma unroll
      for (int m = 0; m < 4; m++) {
        afh[m] = frag_ld(AsH, wr + m * 16 + lr, ks * 4 + lg, sx);
        afl[m] = frag_ld(AsL, wr + m * 16 + lr, ks * 4 + lg, sx);
      }
      #pragma unroll
      for (int n = 0; n < 4; n++) {
        bfh[n] = frag_ld(BsH, wc + n * 16 + lr, ks * 4 + lg, sx);
        bfl[n] = frag_ld(BsL, wc + n * 16 + lr, ks * 4 + lg, sx);
      }
      #pragma unroll
      for (int m = 0; m < 4; m++)
        #pragma unroll
        for (int n = 0; n < 4; n++) {
          acc[m][n] = __builtin_amdgcn_mfma_f32_16x16x32_bf16(afl[m], bfh[n], acc[m][n], 0, 0, 0);
          acc[m][n] = __builtin_amdgcn_mfma_f32_16x16x32_bf16(afh[m], bfl[n], acc[m][n], 0, 0, 0);
          acc[m][n] = __builtin_amdgcn_mfma_f32_16x16x32_bf16(afh[m], bfh[n], acc[m][n], 0, 0, 0);
        }
    }
    __syncthreads();
  }

  #pragma unroll
  for (int m = 0; m < 4; m++)
    #pragma unroll
    for (int n = 0; n < 4; n++)
      #pragma unroll
      for (int r = 0; r < 4; r++) {
        int row = rowA0 + wr + m * 16 + lg * 4 + r;
        int col = rowB0 + wc + n * 16 + lr;
        C[(long)row * NSUP + col] = acc[m][n][r];
      }
}

// ---------------------------------------------------------------------------
// Fused scores + softmax + PV for steps 0-2 (round-17 form, verified 456us;
// M=64, 128 KB LDS, PV STb double-buffered). Frozen.
// ---------------------------------------------------------------------------
__global__ __launch_bounds__(512) void k_sspv(
    const ushort* __restrict__ Ahi,   // Abuf + hoff (ld 768)
    const ushort* __restrict__ Alo,   // Hlo (ld 256)
    const ushort* __restrict__ Shi,   // [512][256]
    const ushort* __restrict__ Slo,   // [512][256]
    const ushort* __restrict__ STb,   // [256][512]
    ushort* __restrict__ Cv)          // Abuf + 256 (ldc LDA_A)
{
  __shared__ ushort SMEM[65536];      // 128 KB
  ushort* Areg = SMEM;                // Ahi 4x[64][64] @0, Alo @16384; later P[64][512]
  ushort* Breg = SMEM + 32768;        // S chunk [512][64]; later scf; later Bpv[2]/elr

  const int tid  = threadIdx.x;
  const int lane = tid & 63;
  const int wave = tid >> 6;
  const int wg = (blockIdx.x & 7) * (gridDim.x >> 3) + (blockIdx.x >> 3);
  const long rowA0 = (long)wg * 64;

  const int lr = lane & 15;
  const int lg = lane >> 4;
  const int sx = lane & 7;

  // ---- stage A (hi: waves 0-3 / lo: waves 4-7; each wave one 64-K chunk) ----
  {
    const ushort* asrc = (wave < 4) ? Ahi : Alo;
    const int ald = (wave < 4) ? LDA_A : D_IN;
    ushort* adst = Areg + (wave >> 2) * 16384 + (wave & 3) * 4096;
    const int ak0 = (wave & 3) * 64;
    #pragma unroll
    for (int q = 0; q < 8; q++)
      stage_rows8(adst, asrc, ald, rowA0, q * 8, ak0, lane);
  }
  // first Shi chunk (kc=0)
  #pragma unroll
  for (int q = 0; q < 8; q++)
    stage_rows8(Breg, Shi, D_IN, 0, wave * 64 + q * 8, 0, lane);
  __syncthreads();

  floatx4 acc[4][4];
  #pragma unroll
  for (int m = 0; m < 4; m++)
    #pragma unroll
    for (int n = 0; n < 4; n++)
      acc[m][n] = (floatx4){0.f, 0.f, 0.f, 0.f};

  for (int kc = 0; kc < 4; kc++) {
    const ushort* Ah = Areg + kc * 4096;
    const ushort* Al = Areg + 16384 + kc * 4096;
    // hi pass: afl*bfh + afh*bfh
    #pragma unroll
    for (int ks = 0; ks < 2; ks++) {
      bhalf8 afh[4], afl[4], bfh[4];
      #pragma unroll
      for (int m = 0; m < 4; m++) {
        afh[m] = frag_ld(Ah, m * 16 + lr, ks * 4 + lg, sx);
        afl[m] = frag_ld(Al, m * 16 + lr, ks * 4 + lg, sx);
      }
      #pragma unroll
      for (int n = 0; n < 4; n++)
        bfh[n] = frag_ld(Breg, wave * 64 + n * 16 + lr, ks * 4 + lg, sx);
      #pragma unroll
      for (int m = 0; m < 4; m++)
        #pragma unroll
        for (int n = 0; n < 4; n++) {
          acc[m][n] = __builtin_amdgcn_mfma_f32_16x16x32_bf16(afl[m], bfh[n], acc[m][n], 0, 0, 0);
          acc[m][n] = __builtin_amdgcn_mfma_f32_16x16x32_bf16(afh[m], bfh[n], acc[m][n], 0, 0, 0);
        }
    }
    __syncthreads();
    // stage Slo chunk into the same buffer
    #pragma unroll
    for (int q = 0; q < 8; q++)
      stage_rows8(Breg, Slo, D_IN, 0, wave * 64 + q * 8, kc * 64, lane);
    __syncthreads();
    // lo pass: afh*bfl
    #pragma unroll
    for (int ks = 0; ks < 2; ks++) {
      bhalf8 afh[4], bfl[4];
      #pragma unroll
      for (int m = 0; m < 4; m++)
        afh[m] = frag_ld(Ah, m * 16 + lr, ks * 4 + lg, sx);
      #pragma unroll
      for (int n = 0; n < 4; n++)
        bfl[n] = frag_ld(Breg, wave * 64 + n * 16 + lr, ks * 4 + lg, sx);
      #pragma unroll
      for (int m = 0; m < 4; m++)
        #pragma unroll
        for (int n = 0; n < 4; n++)
          acc[m][n] = __builtin_amdgcn_mfma_f32_16x16x32_bf16(afh[m], bfl[n], acc[m][n], 0, 0, 0);
    }
    __syncthreads();
    if (kc < 3) {
      #pragma unroll
      for (int q = 0; q < 8; q++)
        stage_rows8(Breg, Shi, D_IN, 0, wave * 64 + q * 8, (kc + 1) * 64, lane);
      __syncthreads();
    }
  }

  // ---- phase 2: scores -> LDS fp32 (two 32-row halves) + softmax -> P ----
  float*  scf = (float*)Breg;         // [32][512] fp32 = 64 KB
  ushort* Ps  = Areg;                 // [64][512] bf16 swizzled (A region dead)
  const int po  = (lane >> 1) & 7;
  const int ph4 = (lane & 1) * 4;
  const int pg0 = lane >> 4;

  #pragma unroll
  for (int half = 0; half < 2; half++) {
    #pragma unroll
    for (int mm = 0; mm < 2; mm++) {
      const int m = half * 2 + mm;
      #pragma unroll
      for (int n = 0; n < 4; n++)
        #pragma unroll
        for (int r = 0; r < 4; r++)
          scf[(mm * 16 + lg * 4 + r) * 512 + wave * 64 + n * 16 + lr] = acc[m][n][r];
    }
    __syncthreads();
    #pragma unroll
    for (int j = 0; j < 4; j++) {
      const int rl = wave * 4 + j;          // row within half (0..31)
      const int r  = half * 32 + rl;        // true local row (0..63)
      const float4* sp = reinterpret_cast<const float4*>(scf + rl * 512);
      float4 v0 = sp[lane];
      float4 v1 = sp[64 + lane];
      float m = fmaxf(fmaxf(fmaxf(v0.x, v0.y), fmaxf(v0.z, v0.w)),
                      fmaxf(fmaxf(v1.x, v1.y), fmaxf(v1.z, v1.w)));
      #pragma unroll
      for (int off = 32; off >= 1; off >>= 1) m = fmaxf(m, __shfl_xor(m, off));
      float e0 = __expf(v0.x - m), e1 = __expf(v0.y - m), e2 = __expf(v0.z - m), e3 = __expf(v0.w - m);
      float e4 = __expf(v1.x - m), e5 = __expf(v1.y - m), e6 = __expf(v1.z - m), e7 = __expf(v1.w - m);
      float s = e0 + e1 + e2 + e3 + e4 + e5 + e6 + e7;
      #pragma unroll
      for (int off = 32; off >= 1; off >>= 1) s += __shfl_xor(s, off);
      float inv = 1.0f / s;
      uint2 p0, p1;
      p0.x = (uint)f2b(e0 * inv) | ((uint)f2b(e1 * inv) << 16);
      p0.y = (uint)f2b(e2 * inv) | ((uint)f2b(e3 * inv) << 16);
      p1.x = (uint)f2b(e4 * inv) | ((uint)f2b(e5 * inv) << 16);
      p1.y = (uint)f2b(e6 * inv) | ((uint)f2b(e7 * inv) << 16);
      const int os = ((po ^ (r & 7)) << 3) + ph4;
      *(uint2*)&Ps[r * 512 + (pg0    ) * 64 + os] = p0;
      *(uint2*)&Ps[r * 512 + (pg0 + 4) * 64 + os] = p1;
    }
    __syncthreads();
  }

  // ---- phase 3: r = P @ STb^T, STb chunks double-buffered (r13 pattern) ----
  floatx4 pacc[4][2];
  #pragma unroll
  for (int m = 0; m < 4; m++)
    #pragma unroll
    for (int n = 0; n < 2; n++)
      pacc[m][n] = (floatx4){0.f, 0.f, 0.f, 0.f};

  ushort* Bpv0 = Breg;                // [256][64] chunk (32 KB)
  ushort* Bpv1 = Breg + 16384;        // second buffer (32 KB)
  #pragma unroll
  for (int q = 0; q < 4; q++)
    stage_rows8(Bpv0, STb, NSUP, 0, wave * 32 + q * 8, 0, lane);
  __syncthreads();
  for (int kc = 0; kc < 8; kc++) {
    ushort* Bcur = (kc & 1) ? Bpv1 : Bpv0;
    ushort* Bnxt = (kc & 1) ? Bpv0 : Bpv1;
    if (kc + 1 < 8) {
      #pragma unroll
      for (int q = 0; q < 4; q++)
        stage_rows8(Bnxt, STb, NSUP, 0, wave * 32 + q * 8, (kc + 1) * 64, lane);
    }
    #pragma unroll
    for (int ks = 0; ks < 2; ks++) {
      bhalf8 af[4], bfr[2];
      #pragma unroll
      for (int m = 0; m < 4; m++)
        af[m] = frag_ld512(Ps, m * 16 + lr, kc, ks * 4 + lg, sx);
      #pragma unroll
      for (int n = 0; n < 2; n++)
        bfr[n] = frag_ld(Bcur, wave * 32 + n * 16 + lr, ks * 4 + lg, sx);
      #pragma unroll
      for (int m = 0; m < 4; m++)
        #pragma unroll
        for (int n = 0; n < 2; n++)
          pacc[m][n] = __builtin_amdgcn_mfma_f32_16x16x32_bf16(af[m], bfr[n], pacc[m][n], 0, 0, 0);
    }
    __syncthreads();
  }

  // ---- epilogue: r [64][256] bf16 via LDS (overlays Bpv0), coalesced ----
  ushort* elr = Breg;                 // 32 KB; all Bpv reads done (final sync)
  #pragma unroll
  for (int m = 0; m < 4; m++)
    #pragma unroll
    for (int n = 0; n < 2; n++)
      #pragma unroll
      for (int r = 0; r < 4; r++)
        elr[(m * 16 + lg * 4 + r) * 256 + wave * 32 + n * 16 + lr] = f2b(pacc[m][n][r]);
  __syncthreads();
  #pragma unroll
  for (int i = tid; i < 2048; i += 512) {
    int row = i >> 5, part = i & 31;
    *(uint4*)(Cv + (rowA0 + row) * LDA_A + part * 8) = ((const uint4*)elr)[i];
  }
}

// ---------------------------------------------------------------------------
// Build permuted live-unit weights + bias + S hi/lo + S^T. (unchanged)
// ---------------------------------------------------------------------------
__global__ __launch_bounds__(256) void k_build(
    const float* __restrict__ Wih, const float* __restrict__ Whh,
    const float* __restrict__ bih, const float* __restrict__ bhh,
    const float* __restrict__ S,
    ushort* __restrict__ We, ushort* __restrict__ Wo, ushort* __restrict__ Wq,
    float4* __restrict__ biasp,
    ushort* __restrict__ Shi, ushort* __restrict__ Slo,
    ushort* __restrict__ STb)
{
  int t = blockIdx.x * 256 + threadIdx.x;
  if (t < GN * 512) {
    int c = t >> 9, k = t & 511;
    int unit = (c >> 6) * 16 + (c & 15);
    int gate = (c >> 4) & 3;
    long srow = (long)(gate * 512 + unit);
    We[(long)c * 512 + k] = f2b(Whh[srow * 512 + k]);
    int ko = (k < 256) ? (256 + k) : (k - 256);
    Wo[(long)c * 512 + k] = f2b(Whh[srow * 512 + ko]);
    if (k < 256) Wq[(long)c * 256 + k] = f2b(Wih[srow * 256 + k]);
  }
  if (t < NUNIT) {
    biasp[t] = make_float4(bih[t] + bhh[t],
                           bih[512 + t] + bhh[512 + t],
                           bih[1024 + t] + bhh[1024 + t],
                           bih[1536 + t] + bhh[1536 + t]);
  }
  if (t < NSUP * D_IN) {
    float v = S[t];
    ushort hv = f2b(v);
    Shi[t] = hv;
    Slo[t] = f2b(v - b2f(hv));
    int s = t >> 8, d = t & 255;
    STb[(long)d * NSUP + s] = hv;
  }
}

// bf16 copy of query (GEMM operand only; epilogues use fp32 query).
__global__ __launch_bounds__(256) void k_initq(
    const float* __restrict__ query, ushort* __restrict__ Qb)
{
  long t = (long)blockIdx.x * 256 + threadIdx.x;
  Qb[t] = f2b(query[t]);
}

// ---------------------------------------------------------------------------
extern "C" void kernel_launch(void* const* d_in, const int* in_sizes, int n_in,
                              void* d_out, int out_size, void* d_ws, size_t ws_size,
                              hipStream_t stream)
{
  const float* support_mean = (const float*)d_in[0];
  const float* query_mean   = (const float*)d_in[2];
  const float* W_ih = (const float*)d_in[4];
  const float* W_hh = (const float*)d_in[5];
  const float* b_ih = (const float*)d_in[6];
  const float* b_hh = (const float*)d_in[7];
  float* out = (float*)d_out;

  char* ws = (char*)d_ws;
  size_t off = 0;
  auto alloc = [&](size_t bytes) {
    void* p = ws + off;
    off += (bytes + 255) & ~(size_t)255;
    return p;
  };
  ushort* Abuf  = (ushort*)alloc((size_t)BATCH_N * LDA_A * 2);  // 50.3 MB
  ushort* Qb    = (ushort*)alloc((size_t)BATCH_N * D_IN * 2);   // 16.8 MB
  ushort* We    = (ushort*)alloc((size_t)GN * 512 * 2);         // 1.05 MB
  ushort* Wo    = (ushort*)alloc((size_t)GN * 512 * 2);         // 1.05 MB
  ushort* Wq    = (ushort*)alloc((size_t)GN * 256 * 2);         // 0.52 MB
  float4* biasp = (float4*)alloc((size_t)NUNIT * 16);
  ushort* Shi   = (ushort*)alloc((size_t)NSUP * D_IN * 2);
  ushort* Slo   = (ushort*)alloc((size_t)NSUP * D_IN * 2);
  ushort* STb   = (ushort*)alloc((size_t)D_IN * NSUP * 2);
  float*  cbuf  = (float*) alloc((size_t)BATCH_N * NUNIT * 4);  // 33.6 MB
  ushort* Hlo   = (ushort*)alloc((size_t)BATCH_N * D_IN * 2);   // 16.8 MB
  uint2*  Gq    = (uint2*) alloc((size_t)BATCH_N * NUNIT * 8);  // 67.1 MB
  if (off > ws_size) return;  // total ~189 MB; >=255 MB proven available

  hipLaunchKernelGGL(k_build, dim3((GN * 512) / 256), dim3(256), 0, stream,
                     W_ih, W_hh, b_ih, b_hh, support_mean,
                     We, Wo, Wq, biasp, Shi, Slo, STb);
  hipLaunchKernelGGL(k_initq, dim3((BATCH_N * D_IN) / 256), dim3(256), 0, stream,
                     query_mean, Qb);

  // Gq = q@Wq^T + b (shared by all steps) + step-0 pointwise -> h_a, c.
  hipLaunchKernelGGL(gemm_gq_fused,
                     dim3((BATCH_N / 128) * (GN / 128)), dim3(512), 0, stream,
                     Qb, Wq, biasp, Gq, cbuf, query_mean, Abuf + 0, Hlo);

  // steps 0-2: fused scores+softmax+PV (no d_out traffic), then next gates.
  for (int s = 0; s < 3; s++) {
    const int hoff = (s & 1) * 512;   // h slot of step s
    hipLaunchKernelGGL(k_sspv, dim3(BATCH_N / 64), dim3(512), 0, stream,
                       Abuf + hoff, Hlo, Shi, Slo, STb, Abuf + 256);
    const int aoff = ((s + 1) == 2) ? 256 : 0;
    const ushort* Wnext = ((s + 1) == 2) ? Wo : We;
    hipLaunchKernelGGL(gemm_gates_fused,
                       dim3((BATCH_N / 128) * (GN / 128)), dim3(512), 0, stream,
                       Abuf + aoff, Wnext, Gq, cbuf, query_mean,
                       Abuf + ((s + 1) & 1) * 512, Hlo);
  }
  // step 3: final scores -> d_out (h in h_b slot, hoff 512)
  hipLaunchKernelGGL(gemm_scores,
                     dim3((BATCH_N / 128) * (NSUP / 128)), dim3(256), 0, stream,
                     Abuf + 512, Hlo, Shi, Slo, out);
}